// Round 2
// baseline (213.677 us; speedup 1.0000x reference)
//
#include <hip/hip_runtime.h>

#define T_N 500000
#define U_N 1000000
#define G_N 250000
#define A_N 20000
#define REC 144   // floats per packed arc record: 8 sidx + 8 lidx + 8*(8 d + 8 s)

// Select r[j] for dynamic j in [0,7] from a register array via cndmask chain.
__device__ __forceinline__ float sel8(const float (&r)[8], int j) {
    float v = r[0];
#pragma unroll
    for (int k = 1; k < 8; ++k) v = (j >= k) ? r[k] : v;
    return v;
}

__device__ __forceinline__ void load8(const float* __restrict__ p, float (&r)[8]) {
    const float4* q = (const float4*)p;
    float4 a = q[0], b = q[1];
    r[0]=a.x; r[1]=a.y; r[2]=a.z; r[3]=a.w;
    r[4]=b.x; r[5]=b.y; r[6]=b.z; r[7]=b.w;
}

// ---------------- softmax (atomic-free, exploits sorted gate_id) ----------------

__global__ void exp_kernel(const float* __restrict__ U, float* __restrict__ wout) {
    int i = blockIdx.x * blockDim.x + threadIdx.x;
    if (i < U_N) wout[i] = expf(U[i]);
}

// Each run-start thread walks its contiguous run and writes the gate sum (no atomics).
__global__ void runsum_kernel(const int* __restrict__ gid,
                              const float* __restrict__ wout,
                              float* __restrict__ gsum) {
    int i = blockIdx.x * blockDim.x + threadIdx.x;
    if (i >= U_N) return;
    int g = gid[i];
    if (i > 0 && gid[i - 1] == g) return;   // not a run start
    float s = 0.0f;
    int j = i;
    do {
        s += wout[j];
        ++j;
    } while (j < U_N && gid[j] == g);
    gsum[g] = s;
}

__global__ void norm_w_kernel(const int* __restrict__ gid,
                              float* __restrict__ wout,
                              const float* __restrict__ gsum) {
    int i = blockIdx.x * blockDim.x + threadIdx.x;
    if (i < U_N) wout[i] = wout[i] / gsum[gid[i]];
}

// ---------------- table repack: [A,REC] packed records ----------------
// rec[0:8] = sidx row, rec[8:16] = lidx row, rec[16+r*16 : 16+r*16+8] = dtab row r,
// rec[16+r*16+8 : 16+(r+1)*16] = stab row r.  Record = 576B = 9 x 64B lines.

__global__ void repack_kernel(const float* __restrict__ dtab,
                              const float* __restrict__ stab,
                              const float* __restrict__ sidx,
                              const float* __restrict__ lidx,
                              float* __restrict__ packed) {
    int i = blockIdx.x * blockDim.x + threadIdx.x;
    if (i >= A_N * REC) return;
    int a = i / REC;
    int e = i - a * REC;
    float v;
    if (e < 8)       v = sidx[a * 8 + e];
    else if (e < 16) v = lidx[a * 8 + (e - 8)];
    else {
        int r = (e - 16) >> 4;
        int c = (e - 16) & 15;
        v = (c < 8) ? dtab[a * 64 + r * 8 + c]
                    : stab[a * 64 + r * 8 + (c - 8)];
    }
    packed[i] = v;
}

// ---------------- timing kernel (packed tables) ----------------

__global__ void __launch_bounds__(256)
timing_packed_kernel(const float2* __restrict__ in_arr,
                     const float2* __restrict__ in_slew,
                     const float* __restrict__ c1,
                     const float* __restrict__ c2,
                     const int* __restrict__ arc_r,
                     const int* __restrict__ arc_f,
                     const int* __restrict__ una,
                     const float* __restrict__ packed,
                     float4* __restrict__ out)
{
    int t = blockIdx.x * blockDim.x + threadIdx.x;
    if (t >= T_N) return;

    float2 ia = in_arr[t];
    float2 is = in_slew[t];
    float c1f = c1[t] / 1.0e15f;
    float c2f = c2[t] / 1.0e15f;
    int arc0 = arc_r[t];
    int arc1 = arc_f[t];

    const float* rec0 = packed + (size_t)arc0 * REC;
    const float* rec1 = packed + (size_t)arc1 * REC;

    // Issue axis-line loads for BOTH columns up front (MLP).
    float s0[8], l0[8], s1[8], l1[8];
    load8(rec0,     s0);
    load8(rec0 + 8, l0);
    load8(rec1,     s1);
    load8(rec1 + 8, l1);
    int u0 = una[arc0];
    int u1 = una[arc1];

    float res_arr[2], res_slew[2];

#pragma unroll
    for (int col = 0; col < 2; ++col) {
        const float* rec = col ? rec1 : rec0;
        int rf = (col ? u1 : u0) ^ col;
        float slew = rf ? is.y : is.x;
        float arr  = rf ? ia.y : ia.x;

        float s[8], cx[8];
#pragma unroll
        for (int k = 0; k < 8; ++k) { s[k] = col ? s1[k] : s0[k]; cx[k] = col ? l1[k] : l0[k]; }

        // slew-axis interval
        int cnt = 0;
#pragma unroll
        for (int k = 0; k < 8; ++k) cnt += (s[k] <= slew) ? 1 : 0;
        int i0 = min(max(cnt - 1, 0), 6);
        float x0 = sel8(s, i0);
        float x1 = sel8(s, i0 + 1);
        float a = (slew - x0) / (x1 - x0);
        float om_a = 1.0f - a;

        // rows i0, i1: each is [d(8) | s(8)] = one 64B line
        const float* row0 = rec + 16 + (size_t)i0 * 16;
        float d0[8], d1[8], t0[8], t1[8];
        load8(row0,      d0);
        load8(row0 + 8,  t0);
        load8(row0 + 16, d1);
        load8(row0 + 24, t1);

        float slew_den = fmaxf(slew, 1e-30f);

        // ceff fixed point: 3 iterations, register-only
        float ceff = fmaxf(c1f + c2f, 1e-30f);
#pragma unroll
        for (int it = 0; it < 3; ++it) {
            int jc = 0;
#pragma unroll
            for (int k = 0; k < 8; ++k) jc += (cx[k] <= ceff) ? 1 : 0;
            int j0 = min(max(jc - 1, 0), 6);
            float y0 = sel8(cx, j0);
            float y1 = sel8(cx, j0 + 1);
            float b = (ceff - y0) / (y1 - y0);
            float om_b = 1.0f - b;
            float v00 = sel8(d0, j0), v01 = sel8(d0, j0 + 1);
            float v10 = sel8(d1, j0), v11 = sel8(d1, j0 + 1);
            float d = om_a * om_b * v00 + om_a * b * v01
                    + a * om_b * v10 + a * b * v11;
            float tau = fmaxf(d, 1e-30f);
            float ratio = fminf(2.0f * tau / slew_den, 10.0f);
            float h = (ratio > 0.01f) ? (1.0f - expf(-ratio)) / ratio
                                      : 1.0f - 0.5f * ratio;
            ceff = fmaxf(c1f + c2f * h, 1e-30f);
        }
        float load = fminf(ceff, 1.0e-12f);

        // final bilinear (delay + slew) from registers
        int jc = 0;
#pragma unroll
        for (int k = 0; k < 8; ++k) jc += (cx[k] <= load) ? 1 : 0;
        int j0 = min(max(jc - 1, 0), 6);
        float y0 = sel8(cx, j0);
        float y1 = sel8(cx, j0 + 1);
        float b = (load - y0) / (y1 - y0);
        float om_b = 1.0f - b;

        float v00 = sel8(d0, j0), v01 = sel8(d0, j0 + 1);
        float v10 = sel8(d1, j0), v11 = sel8(d1, j0 + 1);
        float delay = om_a * om_b * v00 + om_a * b * v01
                    + a * om_b * v10 + a * b * v11;

        float w00 = sel8(t0, j0), w01 = sel8(t0, j0 + 1);
        float w10 = sel8(t1, j0), w11 = sel8(t1, j0 + 1);
        float sl = om_a * om_b * w00 + om_a * b * w01
                 + a * om_b * w10 + a * b * w11;

        res_arr[col]  = arr + delay;
        res_slew[col] = sl;
    }

    out[t] = make_float4(res_arr[0], res_arr[1], res_slew[0], res_slew[1]);
}

// ---------------- fallback timing kernel (unpacked, round-1 version) ----------------

__global__ void __launch_bounds__(256)
timing_kernel(const float2* __restrict__ in_arr,
              const float2* __restrict__ in_slew,
              const float* __restrict__ c1,
              const float* __restrict__ c2,
              const int* __restrict__ arc_r,
              const int* __restrict__ arc_f,
              const int* __restrict__ una,
              const float* __restrict__ dtab,
              const float* __restrict__ stab,
              const float* __restrict__ sidx,
              const float* __restrict__ lidx,
              float4* __restrict__ out)
{
    int t = blockIdx.x * blockDim.x + threadIdx.x;
    if (t >= T_N) return;

    float2 ia = in_arr[t];
    float2 is = in_slew[t];
    float c1f = c1[t] / 1.0e15f;
    float c2f = c2[t] / 1.0e15f;
    int arcs0 = arc_r[t];
    int arcs1 = arc_f[t];

    float res_arr[2], res_slew[2];

#pragma unroll
    for (int col = 0; col < 2; ++col) {
        int arc = (col == 0) ? arcs0 : arcs1;
        int u   = una[arc];
        int rf  = u ^ col;
        float slew = rf ? is.y : is.x;
        float arr  = rf ? ia.y : ia.x;

        float s[8], cx[8];
        load8(sidx + (size_t)arc * 8, s);
        load8(lidx + (size_t)arc * 8, cx);

        int cnt = 0;
#pragma unroll
        for (int k = 0; k < 8; ++k) cnt += (s[k] <= slew) ? 1 : 0;
        int i0 = min(max(cnt - 1, 0), 6);
        float x0 = sel8(s, i0);
        float x1 = sel8(s, i0 + 1);
        float a = (slew - x0) / (x1 - x0);
        float om_a = 1.0f - a;

        float d0[8], d1[8];
        load8(dtab + (size_t)arc * 64 + (size_t)i0 * 8, d0);
        load8(dtab + (size_t)arc * 64 + (size_t)i0 * 8 + 8, d1);

        float slew_den = fmaxf(slew, 1e-30f);
        float ceff = fmaxf(c1f + c2f, 1e-30f);
#pragma unroll
        for (int it = 0; it < 3; ++it) {
            int jc = 0;
#pragma unroll
            for (int k = 0; k < 8; ++k) jc += (cx[k] <= ceff) ? 1 : 0;
            int j0 = min(max(jc - 1, 0), 6);
            float y0 = sel8(cx, j0);
            float y1 = sel8(cx, j0 + 1);
            float b = (ceff - y0) / (y1 - y0);
            float om_b = 1.0f - b;
            float v00 = sel8(d0, j0), v01 = sel8(d0, j0 + 1);
            float v10 = sel8(d1, j0), v11 = sel8(d1, j0 + 1);
            float d = om_a * om_b * v00 + om_a * b * v01
                    + a * om_b * v10 + a * b * v11;
            float tau = fmaxf(d, 1e-30f);
            float ratio = fminf(2.0f * tau / slew_den, 10.0f);
            float h = (ratio > 0.01f) ? (1.0f - expf(-ratio)) / ratio
                                      : 1.0f - 0.5f * ratio;
            ceff = fmaxf(c1f + c2f * h, 1e-30f);
        }
        float load = fminf(ceff, 1.0e-12f);

        int jc = 0;
#pragma unroll
        for (int k = 0; k < 8; ++k) jc += (cx[k] <= load) ? 1 : 0;
        int j0 = min(max(jc - 1, 0), 6);
        float y0 = sel8(cx, j0);
        float y1 = sel8(cx, j0 + 1);
        float b = (load - y0) / (y1 - y0);
        float om_b = 1.0f - b;

        float v00 = sel8(d0, j0), v01 = sel8(d0, j0 + 1);
        float v10 = sel8(d1, j0), v11 = sel8(d1, j0 + 1);
        float delay = om_a * om_b * v00 + om_a * b * v01
                    + a * om_b * v10 + a * b * v11;

        const float* srow = stab + (size_t)arc * 64 + (size_t)i0 * 8;
        float s00 = srow[j0],     s01 = srow[j0 + 1];
        float s10 = srow[8 + j0], s11 = srow[8 + j0 + 1];
        float sl = om_a * om_b * s00 + om_a * b * s01
                 + a * om_b * s10 + a * b * s11;

        res_arr[col]  = arr + delay;
        res_slew[col] = sl;
    }

    out[t] = make_float4(res_arr[0], res_arr[1], res_slew[0], res_slew[1]);
}

extern "C" void kernel_launch(void* const* d_in, const int* in_sizes, int n_in,
                              void* d_out, int out_size, void* d_ws, size_t ws_size,
                              hipStream_t stream) {
    const float*  U      = (const float*)d_in[0];
    const int*    gid    = (const int*)d_in[1];
    const float2* in_arr = (const float2*)d_in[2];
    const float2* in_slw = (const float2*)d_in[3];
    const float*  c1     = (const float*)d_in[4];
    const float*  c2     = (const float*)d_in[5];
    // d_in[6] = rpi : unused by the reference computation
    const int*    arc_r  = (const int*)d_in[7];
    const int*    arc_f  = (const int*)d_in[8];
    const int*    una    = (const int*)d_in[9];
    const float*  dtab   = (const float*)d_in[10];
    const float*  stab   = (const float*)d_in[11];
    const float*  sidx   = (const float*)d_in[12];
    const float*  lidx   = (const float*)d_in[13];

    float* out  = (float*)d_out;
    float* wout = out + (size_t)T_N * 4;

    float* gsum   = (float*)d_ws;                              // G_N floats (1 MB)
    size_t packed_off = (size_t)G_N * sizeof(float);           // 64B-aligned
    float* packed = (float*)((char*)d_ws + packed_off);
    size_t need = packed_off + (size_t)A_N * REC * sizeof(float);

    // softmax (atomic-free; no init kernel needed)
    exp_kernel<<<(U_N + 255) / 256, 256, 0, stream>>>(U, wout);
    runsum_kernel<<<(U_N + 255) / 256, 256, 0, stream>>>(gid, wout, gsum);
    norm_w_kernel<<<(U_N + 255) / 256, 256, 0, stream>>>(gid, wout, gsum);

    if (ws_size >= need) {
        repack_kernel<<<(A_N * REC + 255) / 256, 256, 0, stream>>>(
            dtab, stab, sidx, lidx, packed);
        timing_packed_kernel<<<(T_N + 255) / 256, 256, 0, stream>>>(
            in_arr, in_slw, c1, c2, arc_r, arc_f, una, packed, (float4*)out);
    } else {
        timing_kernel<<<(T_N + 255) / 256, 256, 0, stream>>>(
            in_arr, in_slw, c1, c2, arc_r, arc_f, una, dtab, stab, sidx, lidx,
            (float4*)out);
    }
}

// Round 4
// 206.229 us; speedup vs baseline: 1.0361x; 1.0361x over previous
//
#include <hip/hip_runtime.h>

#define T_N 500000
#define U_N 1000000
#define G_N 250000
#define A_N 20000

// Select r[j] for dynamic j in [0,7] from a register array via cndmask chain.
__device__ __forceinline__ float sel8(const float (&r)[8], int j) {
    float v = r[0];
#pragma unroll
    for (int k = 1; k < 8; ++k) v = (j >= k) ? r[k] : v;
    return v;
}

__device__ __forceinline__ void load8(const float* __restrict__ p, float (&r)[8]) {
    const float4* q = (const float4*)p;
    float4 a = q[0], b = q[1];
    r[0]=a.x; r[1]=a.y; r[2]=a.z; r[3]=a.w;
    r[4]=b.x; r[5]=b.y; r[6]=b.z; r[7]=b.w;
}

// ---------------- fused softmax: each thread resolves its own run ----------------
// gate_id is sorted, avg run length 4. Neighbor loads hit the same cache lines
// the wave already loaded (L1 broadcast). No atomics, no scratch, one dispatch.

__global__ void __launch_bounds__(256)
softmax_kernel(const float* __restrict__ U,
               const int* __restrict__ gid,
               float* __restrict__ wout) {
    int i = blockIdx.x * blockDim.x + threadIdx.x;
    if (i >= U_N) return;
    int g = gid[i];
    float mye = expf(U[i]);
    float s = mye;
    for (int j = i - 1; j >= 0; --j) {
        if (gid[j] != g) break;
        s += expf(U[j]);
    }
    for (int j = i + 1; j < U_N; ++j) {
        if (gid[j] != g) break;
        s += expf(U[j]);
    }
    wout[i] = mye / s;
}

// ---------------- timing kernel (fp32 tables, dual-column overlapped loads) ----------------

__global__ void __launch_bounds__(256)
timing_kernel(const float2* __restrict__ in_arr,
              const float2* __restrict__ in_slew,
              const float* __restrict__ c1,
              const float* __restrict__ c2,
              const int* __restrict__ arc_r,
              const int* __restrict__ arc_f,
              const int* __restrict__ una,
              const float* __restrict__ dtab,   // [A,8,8]
              const float* __restrict__ stab,   // [A,8,8]
              const float* __restrict__ sidx,   // [A,8]
              const float* __restrict__ lidx,   // [A,8]
              float4* __restrict__ out)
{
    int t = blockIdx.x * blockDim.x + threadIdx.x;
    if (t >= T_N) return;

    int arc0 = arc_r[t];
    int arc1 = arc_f[t];

    // ---- issue all axis loads + una for both columns up front ----
    float sA[2][8], cxA[2][8];
    load8(sidx + (size_t)arc0 * 8, sA[0]);
    load8(lidx + (size_t)arc0 * 8, cxA[0]);
    load8(sidx + (size_t)arc1 * 8, sA[1]);
    load8(lidx + (size_t)arc1 * 8, cxA[1]);
    int u0 = una[arc0];
    int u1 = una[arc1];

    float2 ia = in_arr[t];
    float2 is = in_slew[t];
    float c1f = c1[t] / 1.0e15f;
    float c2f = c2[t] / 1.0e15f;

    // ---- compute slew-axis interval for both columns ----
    float slewC[2], arrC[2], aC[2];
    int i0C[2];
    {
        int rf0 = u0;          // col 0: una ^ 0
        int rf1 = u1 ^ 1;      // col 1: una ^ 1
        slewC[0] = rf0 ? is.y : is.x;
        arrC[0]  = rf0 ? ia.y : ia.x;
        slewC[1] = rf1 ? is.y : is.x;
        arrC[1]  = rf1 ? ia.y : ia.x;
#pragma unroll
        for (int col = 0; col < 2; ++col) {
            int cnt = 0;
#pragma unroll
            for (int k = 0; k < 8; ++k) cnt += (sA[col][k] <= slewC[col]) ? 1 : 0;
            int i0 = min(max(cnt - 1, 0), 6);
            float x0 = sel8(sA[col], i0);
            float x1 = sel8(sA[col], i0 + 1);
            aC[col]  = (slewC[col] - x0) / (x1 - x0);
            i0C[col] = i0;
        }
    }

    // ---- issue dtab + stab row loads for both columns before any ceff ALU ----
    float d0A[2][8], d1A[2][8], t0A[2][8], t1A[2][8];
    {
        const float* p0 = dtab + (size_t)arc0 * 64 + (size_t)i0C[0] * 8;
        const float* q0 = stab + (size_t)arc0 * 64 + (size_t)i0C[0] * 8;
        const float* p1 = dtab + (size_t)arc1 * 64 + (size_t)i0C[1] * 8;
        const float* q1 = stab + (size_t)arc1 * 64 + (size_t)i0C[1] * 8;
        load8(p0,     d0A[0]);
        load8(p0 + 8, d1A[0]);
        load8(p1,     d0A[1]);
        load8(p1 + 8, d1A[1]);
        load8(q0,     t0A[0]);
        load8(q0 + 8, t1A[0]);
        load8(q1,     t0A[1]);
        load8(q1 + 8, t1A[1]);
    }

    float res_arr[2], res_slew[2];

#pragma unroll
    for (int col = 0; col < 2; ++col) {
        float a    = aC[col];
        float om_a = 1.0f - a;
        float slew_den = fmaxf(slewC[col], 1e-30f);

        float cx[8], d0[8], d1[8];
#pragma unroll
        for (int k = 0; k < 8; ++k) {
            cx[k] = cxA[col][k];
            d0[k] = d0A[col][k];
            d1[k] = d1A[col][k];
        }

        // ---- ceff fixed point: 3 iterations, register-only ----
        float ceff = fmaxf(c1f + c2f, 1e-30f);
#pragma unroll
        for (int it = 0; it < 3; ++it) {
            int jc = 0;
#pragma unroll
            for (int k = 0; k < 8; ++k) jc += (cx[k] <= ceff) ? 1 : 0;
            int j0 = min(max(jc - 1, 0), 6);
            float y0 = sel8(cx, j0);
            float y1 = sel8(cx, j0 + 1);
            float b = (ceff - y0) / (y1 - y0);
            float om_b = 1.0f - b;
            float v00 = sel8(d0, j0), v01 = sel8(d0, j0 + 1);
            float v10 = sel8(d1, j0), v11 = sel8(d1, j0 + 1);
            float d = om_a * om_b * v00 + om_a * b * v01
                    + a * om_b * v10 + a * b * v11;
            float tau = fmaxf(d, 1e-30f);
            float ratio = fminf(2.0f * tau / slew_den, 10.0f);
            float h = (ratio > 0.01f) ? (1.0f - expf(-ratio)) / ratio
                                      : 1.0f - 0.5f * ratio;
            ceff = fmaxf(c1f + c2f * h, 1e-30f);
        }
        float load = fminf(ceff, 1.0e-12f);

        // ---- final bilinear (delay + slew) from registers ----
        int jc = 0;
#pragma unroll
        for (int k = 0; k < 8; ++k) jc += (cx[k] <= load) ? 1 : 0;
        int j0 = min(max(jc - 1, 0), 6);
        float y0 = sel8(cx, j0);
        float y1 = sel8(cx, j0 + 1);
        float b = (load - y0) / (y1 - y0);
        float om_b = 1.0f - b;

        float v00 = sel8(d0, j0), v01 = sel8(d0, j0 + 1);
        float v10 = sel8(d1, j0), v11 = sel8(d1, j0 + 1);
        float delay = om_a * om_b * v00 + om_a * b * v01
                    + a * om_b * v10 + a * b * v11;

        float w00 = sel8(t0A[col], j0), w01 = sel8(t0A[col], j0 + 1);
        float w10 = sel8(t1A[col], j0), w11 = sel8(t1A[col], j0 + 1);
        float sl = om_a * om_b * w00 + om_a * b * w01
                 + a * om_b * w10 + a * b * w11;

        res_arr[col]  = arrC[col] + delay;
        res_slew[col] = sl;
    }

    out[t] = make_float4(res_arr[0], res_arr[1], res_slew[0], res_slew[1]);
}

extern "C" void kernel_launch(void* const* d_in, const int* in_sizes, int n_in,
                              void* d_out, int out_size, void* d_ws, size_t ws_size,
                              hipStream_t stream) {
    const float*  U      = (const float*)d_in[0];
    const int*    gid    = (const int*)d_in[1];
    const float2* in_arr = (const float2*)d_in[2];
    const float2* in_slw = (const float2*)d_in[3];
    const float*  c1     = (const float*)d_in[4];
    const float*  c2     = (const float*)d_in[5];
    // d_in[6] = rpi : unused by the reference computation
    const int*    arc_r  = (const int*)d_in[7];
    const int*    arc_f  = (const int*)d_in[8];
    const int*    una    = (const int*)d_in[9];
    const float*  dtab   = (const float*)d_in[10];
    const float*  stab   = (const float*)d_in[11];
    const float*  sidx   = (const float*)d_in[12];
    const float*  lidx   = (const float*)d_in[13];

    float* out  = (float*)d_out;               // [T,4] = 2,000,000 floats
    float* wout = out + (size_t)T_N * 4;       // weights = 1,000,000 floats

    softmax_kernel<<<(U_N + 255) / 256, 256, 0, stream>>>(U, gid, wout);

    timing_kernel<<<(T_N + 255) / 256, 256, 0, stream>>>(
        in_arr, in_slw, c1, c2, arc_r, arc_f, una, dtab, stab, sidx, lidx,
        (float4*)out);
}

// Round 5
// 196.318 us; speedup vs baseline: 1.0884x; 1.0505x over previous
//
#include <hip/hip_runtime.h>

#define T_N 500000
#define U_N 1000000
#define G_N 250000
#define A_N 20000

// Select r[j] for dynamic j in [0,7] from a register array via cndmask chain.
__device__ __forceinline__ float sel8(const float (&r)[8], int j) {
    float v = r[0];
#pragma unroll
    for (int k = 1; k < 8; ++k) v = (j >= k) ? r[k] : v;
    return v;
}

__device__ __forceinline__ void load8(const float* __restrict__ p, float (&r)[8]) {
    const float4* q = (const float4*)p;
    float4 a = q[0], b = q[1];
    r[0]=a.x; r[1]=a.y; r[2]=a.z; r[3]=a.w;
    r[4]=b.x; r[5]=b.y; r[6]=b.z; r[7]=b.w;
}

// ---------------- fused softmax: each thread resolves its own run ----------------

__global__ void __launch_bounds__(256)
softmax_kernel(const float* __restrict__ U,
               const int* __restrict__ gid,
               float* __restrict__ wout) {
    int i = blockIdx.x * blockDim.x + threadIdx.x;
    if (i >= U_N) return;
    int g = gid[i];
    float mye = expf(U[i]);
    float s = mye;
    for (int j = i - 1; j >= 0; --j) {
        if (gid[j] != g) break;
        s += expf(U[j]);
    }
    for (int j = i + 1; j < U_N; ++j) {
        if (gid[j] != g) break;
        s += expf(U[j]);
    }
    wout[i] = mye / s;
}

// ---------------- fp32 lossless repack: pack[a][r] = [d_row(8f) | s_row(8f)] ----------------
// 512B per arc, rows i0,i0+1 of BOTH tables land in exactly 2 cache lines.

__global__ void repack_kernel(const float* __restrict__ dtab,
                              const float* __restrict__ stab,
                              float* __restrict__ pack) {
    int i = blockIdx.x * blockDim.x + threadIdx.x;   // [A*128)
    if (i >= A_N * 128) return;
    int a = i >> 7;
    int e = i & 127;
    int r = e >> 4;
    int c = e & 15;
    float v = (c < 8) ? dtab[a * 64 + r * 8 + c]
                      : stab[a * 64 + r * 8 + (c - 8)];
    pack[i] = v;
}

// ---------------- timing kernel: round-1 structure, packed table rows ----------------

__global__ void __launch_bounds__(256)
timing_packed_kernel(const float2* __restrict__ in_arr,
                     const float2* __restrict__ in_slew,
                     const float* __restrict__ c1,
                     const float* __restrict__ c2,
                     const int* __restrict__ arc_r,
                     const int* __restrict__ arc_f,
                     const int* __restrict__ una,
                     const float* __restrict__ pack,   // [A,8,16] = [d8|s8] per row
                     const float* __restrict__ sidx,   // [A,8]
                     const float* __restrict__ lidx,   // [A,8]
                     float4* __restrict__ out)
{
    int t = blockIdx.x * blockDim.x + threadIdx.x;
    if (t >= T_N) return;

    float2 ia = in_arr[t];
    float2 is = in_slew[t];
    float c1f = c1[t] / 1.0e15f;
    float c2f = c2[t] / 1.0e15f;
    int arcs0 = arc_r[t];
    int arcs1 = arc_f[t];

    float res_arr[2], res_slew[2];

#pragma unroll
    for (int col = 0; col < 2; ++col) {
        int arc = (col == 0) ? arcs0 : arcs1;
        int u   = una[arc];
        int rf  = u ^ col;
        float slew = rf ? is.y : is.x;
        float arr  = rf ? ia.y : ia.x;

        float s[8], cx[8];
        load8(sidx + (size_t)arc * 8, s);
        load8(lidx + (size_t)arc * 8, cx);

        int cnt = 0;
#pragma unroll
        for (int k = 0; k < 8; ++k) cnt += (s[k] <= slew) ? 1 : 0;
        int i0 = min(max(cnt - 1, 0), 6);
        float x0 = sel8(s, i0);
        float x1 = sel8(s, i0 + 1);
        float a = (slew - x0) / (x1 - x0);
        float om_a = 1.0f - a;

        // packed rows i0, i0+1: base = pack + arc*128 + i0*16
        const float* base = pack + (size_t)arc * 128 + (size_t)i0 * 16;
        float d0[8], d1[8];
        load8(base,      d0);   // d row i0   (line i0, bytes 0-31)
        load8(base + 16, d1);   // d row i0+1 (line i0+1, bytes 0-31)

        float slew_den = fmaxf(slew, 1e-30f);
        float ceff = fmaxf(c1f + c2f, 1e-30f);
#pragma unroll
        for (int it = 0; it < 3; ++it) {
            int jc = 0;
#pragma unroll
            for (int k = 0; k < 8; ++k) jc += (cx[k] <= ceff) ? 1 : 0;
            int j0 = min(max(jc - 1, 0), 6);
            float y0 = sel8(cx, j0);
            float y1 = sel8(cx, j0 + 1);
            float b = (ceff - y0) / (y1 - y0);
            float om_b = 1.0f - b;
            float v00 = sel8(d0, j0), v01 = sel8(d0, j0 + 1);
            float v10 = sel8(d1, j0), v11 = sel8(d1, j0 + 1);
            float d = om_a * om_b * v00 + om_a * b * v01
                    + a * om_b * v10 + a * b * v11;
            float tau = fmaxf(d, 1e-30f);
            float ratio = fminf(2.0f * tau / slew_den, 10.0f);
            float h = (ratio > 0.01f) ? (1.0f - expf(-ratio)) / ratio
                                      : 1.0f - 0.5f * ratio;
            ceff = fmaxf(c1f + c2f * h, 1e-30f);
        }
        float load = fminf(ceff, 1.0e-12f);

        int jc = 0;
#pragma unroll
        for (int k = 0; k < 8; ++k) jc += (cx[k] <= load) ? 1 : 0;
        int j0 = min(max(jc - 1, 0), 6);
        float y0 = sel8(cx, j0);
        float y1 = sel8(cx, j0 + 1);
        float b = (load - y0) / (y1 - y0);
        float om_b = 1.0f - b;

        float v00 = sel8(d0, j0), v01 = sel8(d0, j0 + 1);
        float v10 = sel8(d1, j0), v11 = sel8(d1, j0 + 1);
        float delay = om_a * om_b * v00 + om_a * b * v01
                    + a * om_b * v10 + a * b * v11;

        // s rows share the SAME 2 lines just fetched: offsets +8 (row i0), +24 (row i0+1)
        float s00 = base[8 + j0],  s01 = base[8 + j0 + 1];
        float s10 = base[24 + j0], s11 = base[24 + j0 + 1];
        float sl = om_a * om_b * s00 + om_a * b * s01
                 + a * om_b * s10 + a * b * s11;

        res_arr[col]  = arr + delay;
        res_slew[col] = sl;
    }

    out[t] = make_float4(res_arr[0], res_arr[1], res_slew[0], res_slew[1]);
}

// ---------------- fallback: round-1 timing kernel (original tables) ----------------

__global__ void __launch_bounds__(256)
timing_kernel(const float2* __restrict__ in_arr,
              const float2* __restrict__ in_slew,
              const float* __restrict__ c1,
              const float* __restrict__ c2,
              const int* __restrict__ arc_r,
              const int* __restrict__ arc_f,
              const int* __restrict__ una,
              const float* __restrict__ dtab,
              const float* __restrict__ stab,
              const float* __restrict__ sidx,
              const float* __restrict__ lidx,
              float4* __restrict__ out)
{
    int t = blockIdx.x * blockDim.x + threadIdx.x;
    if (t >= T_N) return;

    float2 ia = in_arr[t];
    float2 is = in_slew[t];
    float c1f = c1[t] / 1.0e15f;
    float c2f = c2[t] / 1.0e15f;
    int arcs0 = arc_r[t];
    int arcs1 = arc_f[t];

    float res_arr[2], res_slew[2];

#pragma unroll
    for (int col = 0; col < 2; ++col) {
        int arc = (col == 0) ? arcs0 : arcs1;
        int u   = una[arc];
        int rf  = u ^ col;
        float slew = rf ? is.y : is.x;
        float arr  = rf ? ia.y : ia.x;

        float s[8], cx[8];
        load8(sidx + (size_t)arc * 8, s);
        load8(lidx + (size_t)arc * 8, cx);

        int cnt = 0;
#pragma unroll
        for (int k = 0; k < 8; ++k) cnt += (s[k] <= slew) ? 1 : 0;
        int i0 = min(max(cnt - 1, 0), 6);
        float x0 = sel8(s, i0);
        float x1 = sel8(s, i0 + 1);
        float a = (slew - x0) / (x1 - x0);
        float om_a = 1.0f - a;

        float d0[8], d1[8];
        load8(dtab + (size_t)arc * 64 + (size_t)i0 * 8, d0);
        load8(dtab + (size_t)arc * 64 + (size_t)i0 * 8 + 8, d1);

        float slew_den = fmaxf(slew, 1e-30f);
        float ceff = fmaxf(c1f + c2f, 1e-30f);
#pragma unroll
        for (int it = 0; it < 3; ++it) {
            int jc = 0;
#pragma unroll
            for (int k = 0; k < 8; ++k) jc += (cx[k] <= ceff) ? 1 : 0;
            int j0 = min(max(jc - 1, 0), 6);
            float y0 = sel8(cx, j0);
            float y1 = sel8(cx, j0 + 1);
            float b = (ceff - y0) / (y1 - y0);
            float om_b = 1.0f - b;
            float v00 = sel8(d0, j0), v01 = sel8(d0, j0 + 1);
            float v10 = sel8(d1, j0), v11 = sel8(d1, j0 + 1);
            float d = om_a * om_b * v00 + om_a * b * v01
                    + a * om_b * v10 + a * b * v11;
            float tau = fmaxf(d, 1e-30f);
            float ratio = fminf(2.0f * tau / slew_den, 10.0f);
            float h = (ratio > 0.01f) ? (1.0f - expf(-ratio)) / ratio
                                      : 1.0f - 0.5f * ratio;
            ceff = fmaxf(c1f + c2f * h, 1e-30f);
        }
        float load = fminf(ceff, 1.0e-12f);

        int jc = 0;
#pragma unroll
        for (int k = 0; k < 8; ++k) jc += (cx[k] <= load) ? 1 : 0;
        int j0 = min(max(jc - 1, 0), 6);
        float y0 = sel8(cx, j0);
        float y1 = sel8(cx, j0 + 1);
        float b = (load - y0) / (y1 - y0);
        float om_b = 1.0f - b;

        float v00 = sel8(d0, j0), v01 = sel8(d0, j0 + 1);
        float v10 = sel8(d1, j0), v11 = sel8(d1, j0 + 1);
        float delay = om_a * om_b * v00 + om_a * b * v01
                    + a * om_b * v10 + a * b * v11;

        const float* srow = stab + (size_t)arc * 64 + (size_t)i0 * 8;
        float s00 = srow[j0],     s01 = srow[j0 + 1];
        float s10 = srow[8 + j0], s11 = srow[8 + j0 + 1];
        float sl = om_a * om_b * s00 + om_a * b * s01
                 + a * om_b * s10 + a * b * s11;

        res_arr[col]  = arr + delay;
        res_slew[col] = sl;
    }

    out[t] = make_float4(res_arr[0], res_arr[1], res_slew[0], res_slew[1]);
}

extern "C" void kernel_launch(void* const* d_in, const int* in_sizes, int n_in,
                              void* d_out, int out_size, void* d_ws, size_t ws_size,
                              hipStream_t stream) {
    const float*  U      = (const float*)d_in[0];
    const int*    gid    = (const int*)d_in[1];
    const float2* in_arr = (const float2*)d_in[2];
    const float2* in_slw = (const float2*)d_in[3];
    const float*  c1     = (const float*)d_in[4];
    const float*  c2     = (const float*)d_in[5];
    // d_in[6] = rpi : unused by the reference computation
    const int*    arc_r  = (const int*)d_in[7];
    const int*    arc_f  = (const int*)d_in[8];
    const int*    una    = (const int*)d_in[9];
    const float*  dtab   = (const float*)d_in[10];
    const float*  stab   = (const float*)d_in[11];
    const float*  sidx   = (const float*)d_in[12];
    const float*  lidx   = (const float*)d_in[13];

    float* out  = (float*)d_out;               // [T,4] = 2,000,000 floats
    float* wout = out + (size_t)T_N * 4;       // weights = 1,000,000 floats

    float* pack = (float*)d_ws;
    size_t need = (size_t)A_N * 128 * sizeof(float);   // 10.24 MB

    softmax_kernel<<<(U_N + 255) / 256, 256, 0, stream>>>(U, gid, wout);

    if (ws_size >= need) {
        repack_kernel<<<(A_N * 128 + 255) / 256, 256, 0, stream>>>(dtab, stab, pack);
        timing_packed_kernel<<<(T_N + 255) / 256, 256, 0, stream>>>(
            in_arr, in_slw, c1, c2, arc_r, arc_f, una, pack, sidx, lidx,
            (float4*)out);
    } else {
        timing_kernel<<<(T_N + 255) / 256, 256, 0, stream>>>(
            in_arr, in_slw, c1, c2, arc_r, arc_f, una, dtab, stab, sidx, lidx,
            (float4*)out);
    }
}

// Round 6
// 172.116 us; speedup vs baseline: 1.2415x; 1.1406x over previous
//
#include <hip/hip_runtime.h>

#define T_N 500000
#define U_N 1000000
#define G_N 250000
#define A_N 20000

#define SBLK 256
#define HALO 96   // max supported run overhang; max observed run ~20 (Poisson(4) tail)

// Select r[j] for dynamic j in [0,7] from a register array via cndmask chain.
__device__ __forceinline__ float sel8(const float (&r)[8], int j) {
    float v = r[0];
#pragma unroll
    for (int k = 1; k < 8; ++k) v = (j >= k) ? r[k] : v;
    return v;
}

__device__ __forceinline__ void load8(const float* __restrict__ p, float (&r)[8]) {
    const float4* q = (const float4*)p;
    float4 a = q[0], b = q[1];
    r[0]=a.x; r[1]=a.y; r[2]=a.z; r[3]=a.w;
    r[4]=b.x; r[5]=b.y; r[6]=b.z; r[7]=b.w;
}

// ---------------- LDS-windowed softmax: one pass, no atomics ----------------
// Block loads [base-HALO, base+SBLK+HALO) of gid and exp(U) into LDS (coalesced,
// expf once per element). Each thread scans its run inside LDS (~5 cyc/iter
// instead of a serialized ~100+ cyc dependent global-load walk).

__global__ void __launch_bounds__(256)
softmax_lds_kernel(const float* __restrict__ U,
                   const int* __restrict__ gid,
                   float* __restrict__ wout) {
    __shared__ float se[SBLK + 2 * HALO];
    __shared__ int   sg[SBLK + 2 * HALO];

    int base = blockIdx.x * SBLK;
    int wstart = base - HALO;

    for (int k = threadIdx.x; k < SBLK + 2 * HALO; k += SBLK) {
        int idx = wstart + k;
        if (idx >= 0 && idx < U_N) {
            se[k] = expf(U[idx]);
            sg[k] = gid[idx];
        } else {
            se[k] = 0.0f;
            sg[k] = -1 - k;   // unique sentinel, never matches a real gate id
        }
    }
    __syncthreads();

    int i = base + threadIdx.x;
    if (i >= U_N) return;

    int li = threadIdx.x + HALO;
    int g = sg[li];
    float mye = se[li];
    float s = mye;
    for (int j = li - 1; j >= 0 && sg[j] == g; --j) s += se[j];
    for (int j = li + 1; j < SBLK + 2 * HALO && sg[j] == g; ++j) s += se[j];

    wout[i] = mye / s;
}

// ---------------- timing kernel (round-1 structure, fp32 tables) ----------------

__global__ void __launch_bounds__(256)
timing_kernel(const float2* __restrict__ in_arr,
              const float2* __restrict__ in_slew,
              const float* __restrict__ c1,
              const float* __restrict__ c2,
              const int* __restrict__ arc_r,
              const int* __restrict__ arc_f,
              const int* __restrict__ una,
              const float* __restrict__ dtab,   // [A,8,8]
              const float* __restrict__ stab,   // [A,8,8]
              const float* __restrict__ sidx,   // [A,8]
              const float* __restrict__ lidx,   // [A,8]
              float4* __restrict__ out)
{
    int t = blockIdx.x * blockDim.x + threadIdx.x;
    if (t >= T_N) return;

    float2 ia = in_arr[t];
    float2 is = in_slew[t];
    float c1f = c1[t] / 1.0e15f;
    float c2f = c2[t] / 1.0e15f;
    int arcs0 = arc_r[t];
    int arcs1 = arc_f[t];

    float res_arr[2], res_slew[2];

#pragma unroll
    for (int col = 0; col < 2; ++col) {
        int arc = (col == 0) ? arcs0 : arcs1;
        int u   = una[arc];
        int rf  = u ^ col;
        float slew = rf ? is.y : is.x;
        float arr  = rf ? ia.y : ia.x;

        float s[8], cx[8];
        load8(sidx + (size_t)arc * 8, s);
        load8(lidx + (size_t)arc * 8, cx);

        int cnt = 0;
#pragma unroll
        for (int k = 0; k < 8; ++k) cnt += (s[k] <= slew) ? 1 : 0;
        int i0 = min(max(cnt - 1, 0), 6);
        float x0 = sel8(s, i0);
        float x1 = sel8(s, i0 + 1);
        float a = (slew - x0) / (x1 - x0);
        float om_a = 1.0f - a;

        float d0[8], d1[8];
        load8(dtab + (size_t)arc * 64 + (size_t)i0 * 8, d0);
        load8(dtab + (size_t)arc * 64 + (size_t)i0 * 8 + 8, d1);

        float slew_den = fmaxf(slew, 1e-30f);
        float ceff = fmaxf(c1f + c2f, 1e-30f);
#pragma unroll
        for (int it = 0; it < 3; ++it) {
            int jc = 0;
#pragma unroll
            for (int k = 0; k < 8; ++k) jc += (cx[k] <= ceff) ? 1 : 0;
            int j0 = min(max(jc - 1, 0), 6);
            float y0 = sel8(cx, j0);
            float y1 = sel8(cx, j0 + 1);
            float b = (ceff - y0) / (y1 - y0);
            float om_b = 1.0f - b;
            float v00 = sel8(d0, j0), v01 = sel8(d0, j0 + 1);
            float v10 = sel8(d1, j0), v11 = sel8(d1, j0 + 1);
            float d = om_a * om_b * v00 + om_a * b * v01
                    + a * om_b * v10 + a * b * v11;
            float tau = fmaxf(d, 1e-30f);
            float ratio = fminf(2.0f * tau / slew_den, 10.0f);
            float h = (ratio > 0.01f) ? (1.0f - expf(-ratio)) / ratio
                                      : 1.0f - 0.5f * ratio;
            ceff = fmaxf(c1f + c2f * h, 1e-30f);
        }
        float load = fminf(ceff, 1.0e-12f);

        int jc = 0;
#pragma unroll
        for (int k = 0; k < 8; ++k) jc += (cx[k] <= load) ? 1 : 0;
        int j0 = min(max(jc - 1, 0), 6);
        float y0 = sel8(cx, j0);
        float y1 = sel8(cx, j0 + 1);
        float b = (load - y0) / (y1 - y0);
        float om_b = 1.0f - b;

        float v00 = sel8(d0, j0), v01 = sel8(d0, j0 + 1);
        float v10 = sel8(d1, j0), v11 = sel8(d1, j0 + 1);
        float delay = om_a * om_b * v00 + om_a * b * v01
                    + a * om_b * v10 + a * b * v11;

        const float* srow = stab + (size_t)arc * 64 + (size_t)i0 * 8;
        float s00 = srow[j0],     s01 = srow[j0 + 1];
        float s10 = srow[8 + j0], s11 = srow[8 + j0 + 1];
        float sl = om_a * om_b * s00 + om_a * b * s01
                 + a * om_b * s10 + a * b * s11;

        res_arr[col]  = arr + delay;
        res_slew[col] = sl;
    }

    out[t] = make_float4(res_arr[0], res_arr[1], res_slew[0], res_slew[1]);
}

extern "C" void kernel_launch(void* const* d_in, const int* in_sizes, int n_in,
                              void* d_out, int out_size, void* d_ws, size_t ws_size,
                              hipStream_t stream) {
    const float*  U      = (const float*)d_in[0];
    const int*    gid    = (const int*)d_in[1];
    const float2* in_arr = (const float2*)d_in[2];
    const float2* in_slw = (const float2*)d_in[3];
    const float*  c1     = (const float*)d_in[4];
    const float*  c2     = (const float*)d_in[5];
    // d_in[6] = rpi : unused by the reference computation
    const int*    arc_r  = (const int*)d_in[7];
    const int*    arc_f  = (const int*)d_in[8];
    const int*    una    = (const int*)d_in[9];
    const float*  dtab   = (const float*)d_in[10];
    const float*  stab   = (const float*)d_in[11];
    const float*  sidx   = (const float*)d_in[12];
    const float*  lidx   = (const float*)d_in[13];

    float* out  = (float*)d_out;               // [T,4] = 2,000,000 floats
    float* wout = out + (size_t)T_N * 4;       // weights = 1,000,000 floats

    softmax_lds_kernel<<<(U_N + SBLK - 1) / SBLK, SBLK, 0, stream>>>(U, gid, wout);

    timing_kernel<<<(T_N + 255) / 256, 256, 0, stream>>>(
        in_arr, in_slw, c1, c2, arc_r, arc_f, una, dtab, stab, sidx, lidx,
        (float4*)out);
}